// Round 6
// baseline (5726.305 us; speedup 1.0000x reference)
//
#include <hip/hip_runtime.h>
#include <cstdint>
#include <cstddef>

#define H 512
#define SS 20
#define BB 16
#define LL 30
#define NN 6
#define TT 20
#define VT 30000
#define MROWS 1824   /* N*B*(T-1) */
#define NSTEPS 114   /* N*(T-1) */
#define MPAD 1856    /* 29*64 */
#define NT2 120      /* 8 chunks * 15 tiles of 256 */
#define VBLK 232     /* 29 mt * 8 chunks */
#define UBLK 16

#define SCOPE_AGENT __HIP_MEMORY_SCOPE_AGENT

typedef __attribute__((ext_vector_type(8))) short bf16x8;
typedef __attribute__((ext_vector_type(4))) float f32x4;

__device__ __forceinline__ float sigmoidf_(float x) { return 1.f / (1.f + expf(-x)); }
__device__ __forceinline__ float b2f(ushort u) { return __uint_as_float(((uint32_t)u) << 16); }
__device__ __forceinline__ ushort f2b_rne(float f) {
  uint32_t u = __float_as_uint(f);
  return (ushort)((u + 0x7fffu + ((u >> 16) & 1u)) >> 16);
}

// ---- fence-free coherence-point accessors (relaxed agent-scope atomics) ----
__device__ __forceinline__ void ast_u32(uint* p, uint v) {
  __hip_atomic_store(p, v, __ATOMIC_RELAXED, SCOPE_AGENT);
}
__device__ __forceinline__ uint ald_u32(const uint* p) {
  return __hip_atomic_load(p, __ATOMIC_RELAXED, SCOPE_AGENT);
}
__device__ __forceinline__ void ast_f32(float* p, float v) {
  __hip_atomic_store(p, v, __ATOMIC_RELAXED, SCOPE_AGENT);
}
__device__ __forceinline__ float ald_f32(const float* p) {
  return __hip_atomic_load(p, __ATOMIC_RELAXED, SCOPE_AGENT);
}
union BF8U { unsigned long long u[2]; bf16x8 v; };
__device__ __forceinline__ bf16x8 ald_bf8(const ushort* p) {
  const unsigned long long* q = (const unsigned long long*)p;
  BF8U r;
  r.u[0] = __hip_atomic_load(q,     __ATOMIC_RELAXED, SCOPE_AGENT);
  r.u[1] = __hip_atomic_load(q + 1, __ATOMIC_RELAXED, SCOPE_AGENT);
  return r.v;
}
// lanes (2i,2i+1) hold bf16 for adjacent units of the SAME row; even lane
// packs both into one 4B coherence-point store at [row][unit&~1].
__device__ __forceinline__ void ast_pair(ushort* addr_even, ushort myv, int lane) {
  uint other = __shfl_xor((uint)myv, 1);
  if (!(lane & 1)) ast_u32((uint*)addr_even, (uint)myv | (other << 16));
}

// ---------------------------------------------------------------------------
// fence-free flag barrier: per-block flag (64B apart), monotone phase value.
// Arrival = one relaxed store; wait = 16 lanes poll 16 flags in parallel.
// Data ordering: __syncthreads() drains each wave's vmcnt before arrival, so
// all prior coherence-point stores are acked before the flag store issues.
// ---------------------------------------------------------------------------
__device__ __forceinline__ void fbar(uint* flags, int bid, int nblk, uint phase)
{
  __syncthreads();
  if (threadIdx.x == 0)
    ast_u32(&flags[bid * 16], phase);
  if ((int)threadIdx.x < nblk) {
    while (ald_u32(&flags[threadIdx.x * 16]) < phase)
      __builtin_amdgcn_s_sleep(1);
  }
  __syncthreads();
}

// legacy fenced barrier (vocab kernel only: its W-conversion uses normal
// stores, which need the acq/rel L2 writeback/invalidate for cross-XCD)
__device__ __forceinline__ void gbar(uint* cnt, uint* gen, uint nblk)
{
  __syncthreads();
  if (threadIdx.x == 0) {
    uint g = __hip_atomic_load(gen, __ATOMIC_RELAXED, SCOPE_AGENT);
    uint v = __hip_atomic_fetch_add(cnt, 1u, __ATOMIC_ACQ_REL, SCOPE_AGENT);
    if (v == nblk - 1u) {
      __hip_atomic_store(cnt, 0u, __ATOMIC_RELAXED, SCOPE_AGENT);
      __hip_atomic_store(gen, g + 1u, __ATOMIC_RELEASE, SCOPE_AGENT);
    } else {
      while (__hip_atomic_load(gen, __ATOMIC_ACQUIRE, SCOPE_AGENT) == g)
        __builtin_amdgcn_s_sleep(2);
    }
  }
  __syncthreads();
}

// ---------------------------------------------------------------------------
// prep: token gathers -> bf16 A matrices; weight matrices f32 -> bf16
// ---------------------------------------------------------------------------
struct PrepP {
  const int* articles; const int* summaries;
  const float* emb_src; const float* emb_tgt;
  const float* we_Wi; const float* wd_Wi; const float* we_Wh;
  const float* se_Wi; const float* se_Wh; const float* W_feat;
  const float* wd_Wh; const float* sd_Wi; const float* sd_Wh;
  const float* attn_Wh; const float* W_out;
  ushort* A_we; ushort* A_wd;
  ushort* weWi; ushort* wdWi; ushort* weWh;
  ushort* seWi; ushort* seWh; ushort* wfeat;
  ushort* wdWh; ushort* sdWi; ushort* sdWh;
  ushort* attnWh; ushort* Wout;
};

__device__ __forceinline__ void conv_f2b(const float* __restrict__ src,
                                         ushort* __restrict__ dst, int n4,
                                         int t0, int stride)
{
  for (int i = t0; i < n4; i += stride) {
    float4 v = reinterpret_cast<const float4*>(src)[i];
    ushort4 o;
    o.x = f2b_rne(v.x); o.y = f2b_rne(v.y);
    o.z = f2b_rne(v.z); o.w = f2b_rne(v.w);
    reinterpret_cast<ushort4*>(dst)[i] = o;
  }
}

__global__ __launch_bounds__(256) void prep_kernel(PrepP P)
{
  const int t0 = blockIdx.x * 256 + threadIdx.x;
  const int stride = gridDim.x * 256;
  for (int i = t0; i < SS * BB * LL * H; i += stride) {
    int m = i >> 9, k = i & 511;
    int l = m / (SS * BB), sb = m % (SS * BB);
    int tok = P.articles[sb * LL + l];
    P.A_we[i] = f2b_rne(P.emb_src[(size_t)tok * H + k]);
  }
  for (int i = t0; i < MROWS * H; i += stride) {
    int m = i >> 9, k = i & 511;
    int stp = m >> 4, b = m & 15;
    int n = stp / (TT - 1), t = stp % (TT - 1);
    int tok = P.summaries[(n * BB + b) * TT + t];
    P.A_wd[i] = f2b_rne(P.emb_tgt[(size_t)tok * H + k]);
  }
  const int Q = 4 * H * H / 4;
  conv_f2b(P.we_Wi, P.weWi, Q, t0, stride);
  conv_f2b(P.wd_Wi, P.wdWi, Q, t0, stride);
  conv_f2b(P.we_Wh, P.weWh, Q, t0, stride);
  conv_f2b(P.se_Wi, P.seWi, Q, t0, stride);
  conv_f2b(P.se_Wh, P.seWh, Q, t0, stride);
  conv_f2b(P.wd_Wh, P.wdWh, Q, t0, stride);
  conv_f2b(P.sd_Wi, P.sdWi, Q, t0, stride);
  conv_f2b(P.sd_Wh, P.sdWh, Q, t0, stride);
  conv_f2b(P.W_feat, P.wfeat, H * H / 4, t0, stride);
  conv_f2b(P.attn_Wh, P.attnWh, H * H / 4, t0, stride);
  conv_f2b(P.W_out, P.Wout, H * 2 * H / 4, t0, stride);
}

// ---------------------------------------------------------------------------
// bf16 MFMA input projections: Xi = A @ Wi^T + b  (bf16 out, [M][2048])
// ---------------------------------------------------------------------------
__global__ __launch_bounds__(512) void proj_mfma_kernel(
    const ushort* __restrict__ A_we, const ushort* __restrict__ weWi,
    const float* __restrict__ we_b, ushort* __restrict__ XiW,
    const ushort* __restrict__ A_wd, const ushort* __restrict__ wdWi,
    const float* __restrict__ wd_b, ushort* __restrict__ XiD)
{
  int bid = blockIdx.x;
  const ushort* A; const ushort* W; const float* bias; ushort* C; int M, mt, nt;
  if (bid < 1200) { A = A_we; W = weWi; bias = we_b; C = XiW; M = 9600; mt = bid >> 3; nt = bid & 7; }
  else { int b2 = bid - 1200; A = A_wd; W = wdWi; bias = wd_b; C = XiD; M = MROWS; mt = b2 >> 3; nt = b2 & 7; }
  const int tid = threadIdx.x, wid = tid >> 6, lane = tid & 63;
  const int wm = wid >> 2, wn = wid & 3;
  const int m0 = mt * 64 + wm * 32, n0 = nt * 256 + wn * 64;
  const int lr = lane & 15, lk = (lane >> 4) << 3;

  f32x4 acc[2][4];
#pragma unroll
  for (int i = 0; i < 2; ++i)
#pragma unroll
    for (int nf = 0; nf < 4; ++nf) acc[i][nf] = (f32x4)0.0f;

  for (int k0 = 0; k0 < H; k0 += 32) {
    bf16x8 a[2], b[4];
#pragma unroll
    for (int i = 0; i < 2; ++i) {
      int m = m0 + i * 16 + lr;
      bf16x8 az = (bf16x8)(short)0;
      if (m < M) az = *reinterpret_cast<const bf16x8*>(A + (size_t)m * H + k0 + lk);
      a[i] = az;
    }
#pragma unroll
    for (int nf = 0; nf < 4; ++nf)
      b[nf] = *reinterpret_cast<const bf16x8*>(W + (size_t)(n0 + nf * 16 + lr) * H + k0 + lk);
#pragma unroll
    for (int i = 0; i < 2; ++i)
#pragma unroll
      for (int nf = 0; nf < 4; ++nf)
        acc[i][nf] = __builtin_amdgcn_mfma_f32_16x16x32_bf16(a[i], b[nf], acc[i][nf], 0, 0, 0);
  }
#pragma unroll
  for (int i = 0; i < 2; ++i)
#pragma unroll
    for (int nf = 0; nf < 4; ++nf) {
      int n = n0 + nf * 16 + lr;
      float bv = bias[n];
#pragma unroll
      for (int jreg = 0; jreg < 4; ++jreg) {
        int row = m0 + i * 16 + (lane >> 4) * 4 + jreg;
        if (row < M) C[(size_t)row * 2048 + n] = f2b_rne(acc[i][nf][jreg] + bv);
      }
    }
}

// ---------------------------------------------------------------------------
// unified sequential kernel with fence-free barriers + coherence-point data.
// 16 blocks x 512 threads. Immutable data (weights, XiW/XiD) = normal loads;
// all intra-kernel cross-block state = relaxed agent atomics.
// ---------------------------------------------------------------------------
struct UP {
  const ushort* XiW; const ushort* XiD;
  const ushort* weWh; const ushort* seWi; const ushort* seWh;
  const ushort* wfeat; const ushort* wdWh; const ushort* sdWi;
  const ushort* sdWh; const ushort* attnWh; const ushort* Wout;
  const float* se_b; const float* b_feat; const float* sd_b; const float* b_out;
  const float* attn_wc; const float* attn_v; const int* articles;
  ushort* h0; ushort* h1;
  float* XiS;
  ushort* sh0; ushort* sh1;
  float* sent_out; ushort* sent_out_bf; float* sent_feat;
  ushort* wh_bf; ushort* sdh_bf; ushort* final_bf; ushort* catb;
  float* qb; float* ebuf; float* alignb; float* covb; float* loss;
  uint* flags;
};

__global__ __launch_bounds__(512) void uni_kernel(UP P)
{
  __shared__ f32x4 hred[2][4][64];
  const int tid = threadIdx.x, bid = blockIdx.x;
  const int wid = tid >> 6, lane = tid & 63;
  const int gw = bid * 8 + wid;
  const int lr = lane & 15;
  const int lk = (lane >> 4) << 3;
  const int orow = (lane >> 4) << 2;
  uint ph = 0;

  // ================= word encoder: 30 steps, M=320 =================
  {
    float cst[5][4];
#pragma unroll
    for (int it = 0; it < 5; ++it)
#pragma unroll
      for (int rg = 0; rg < 4; ++rg) cst[it][rg] = 0.f;
    ushort* cur = P.h0;
    ushort* nxt = P.h1;
    const int ug = gw & 31;
    const int unit = ug * 16 + lr;
    const ushort* wb = P.weWh + (size_t)(ug * 16 + lr) * H + lk;
    for (int l = 0; l < LL; ++l) {
#pragma unroll
      for (int it = 0; it < 5; ++it) {
        int mt = (gw + it * 128) >> 5;
        f32x4 acc[4];
#pragma unroll
        for (int g = 0; g < 4; ++g) acc[g] = (f32x4)0.0f;
        const ushort* ab = cur + (size_t)(mt * 16 + lr) * H + lk;
#pragma unroll
        for (int k0 = 0; k0 < H; k0 += 32) {
          bf16x8 a = ald_bf8(ab + k0);
#pragma unroll
          for (int g = 0; g < 4; ++g) {
            bf16x8 b = *reinterpret_cast<const bf16x8*>(wb + (size_t)g * H * H + k0);
            acc[g] = __builtin_amdgcn_mfma_f32_16x16x32_bf16(a, b, acc[g], 0, 0, 0);
          }
        }
#pragma unroll
        for (int rg = 0; rg < 4; ++rg) {
          int row = mt * 16 + orow + rg;
          const ushort* xi = P.XiW + (size_t)(l * 320 + row) * 2048 + unit;
          float gi = acc[0][rg] + b2f(xi[0]);
          float gf = acc[1][rg] + b2f(xi[512]);
          float gc = acc[2][rg] + b2f(xi[1024]);
          float go = acc[3][rg] + b2f(xi[1536]);
          float c = sigmoidf_(gf) * cst[it][rg] + sigmoidf_(gi) * tanhf(gc);
          float h = sigmoidf_(go) * tanhf(c);
          cst[it][rg] = c;
          ast_pair(nxt + (size_t)row * H + (unit & ~1), f2b_rne(h), lane);
        }
      }
      fbar(P.flags, bid, UBLK, ++ph);
      ushort* t = cur; cur = nxt; nxt = t;
    }
    // ---- XiS = h30 @ se_Wi^T + se_b (f32, coherence-point stores) ----
    {
      const ushort* wbs = P.seWi + (size_t)(ug * 16 + lr) * H + lk;
#pragma unroll
      for (int it = 0; it < 5; ++it) {
        int mt = (gw + it * 128) >> 5;
        f32x4 acc[4];
#pragma unroll
        for (int g = 0; g < 4; ++g) acc[g] = (f32x4)0.0f;
        const ushort* ab = cur + (size_t)(mt * 16 + lr) * H + lk;
#pragma unroll
        for (int k0 = 0; k0 < H; k0 += 32) {
          bf16x8 a = ald_bf8(ab + k0);
#pragma unroll
          for (int g = 0; g < 4; ++g) {
            bf16x8 b = *reinterpret_cast<const bf16x8*>(wbs + (size_t)g * H * H + k0);
            acc[g] = __builtin_amdgcn_mfma_f32_16x16x32_bf16(a, b, acc[g], 0, 0, 0);
          }
        }
#pragma unroll
        for (int rg = 0; rg < 4; ++rg) {
          int row = mt * 16 + orow + rg;
#pragma unroll
          for (int g = 0; g < 4; ++g)
            ast_f32(&P.XiS[(size_t)row * 2048 + g * H + unit],
                    acc[g][rg] + P.se_b[g * H + unit]);
        }
      }
    }
    fbar(P.flags, bid, UBLK, ++ph);
  }

  // ================= sentence encoder: 20 steps, M=16 =================
  float cw[4] = {0.f, 0.f, 0.f, 0.f};
  float csd[4] = {0.f, 0.f, 0.f, 0.f};
  {
    float cse[4] = {0.f, 0.f, 0.f, 0.f};
    ushort* cur = P.sh0;
    ushort* nxt = P.sh1;
    const int ug = bid * 2 + wid;        // valid when wid<2
    const int unit = ug * 16 + lr;
    for (int s = 0; s < SS; ++s) {
      if (wid < 2) {
        f32x4 acc[4];
#pragma unroll
        for (int g = 0; g < 4; ++g) acc[g] = (f32x4)0.0f;
        const ushort* ab = cur + (size_t)lr * H + lk;
        const ushort* wb = P.seWh + (size_t)(ug * 16 + lr) * H + lk;
#pragma unroll
        for (int k0 = 0; k0 < H; k0 += 32) {
          bf16x8 a = ald_bf8(ab + k0);
#pragma unroll
          for (int g = 0; g < 4; ++g) {
            bf16x8 b = *reinterpret_cast<const bf16x8*>(wb + (size_t)g * H * H + k0);
            acc[g] = __builtin_amdgcn_mfma_f32_16x16x32_bf16(a, b, acc[g], 0, 0, 0);
          }
        }
#pragma unroll
        for (int rg = 0; rg < 4; ++rg) {
          int row = orow + rg;
          float gi = acc[0][rg] + ald_f32(&P.XiS[(size_t)(s * 16 + row) * 2048 + 0 * H + unit]);
          float gf = acc[1][rg] + ald_f32(&P.XiS[(size_t)(s * 16 + row) * 2048 + 1 * H + unit]);
          float gc = acc[2][rg] + ald_f32(&P.XiS[(size_t)(s * 16 + row) * 2048 + 2 * H + unit]);
          float go = acc[3][rg] + ald_f32(&P.XiS[(size_t)(s * 16 + row) * 2048 + 3 * H + unit]);
          float c = sigmoidf_(gf) * cse[rg] + sigmoidf_(gi) * tanhf(gc);
          float h = sigmoidf_(go) * tanhf(c);
          cse[rg] = c;
          ushort hv = f2b_rne(h);
          uint other = __shfl_xor((uint)hv, 1);
          if (!(lane & 1)) {
            uint pk = (uint)hv | (other << 16);
            ast_u32((uint*)(nxt + (size_t)row * H + (unit & ~1)), pk);
            ast_u32((uint*)(P.sent_out_bf + (size_t)(s * 16 + row) * H + (unit & ~1)), pk);
          }
          ast_f32(&P.sent_out[(size_t)(s * 16 + row) * H + unit], h);
        }
      }
      fbar(P.flags, bid, UBLK, ++ph);
      ushort* t = cur; cur = nxt; nxt = t;
    }
    // transfer cse -> cw holders (wid 0,2) via LDS; csd stays on wid<2
    if (wid < 2) {
      f32x4 v; v[0] = cse[0]; v[1] = cse[1]; v[2] = cse[2]; v[3] = cse[3];
      hred[wid][0][lane] = v;
#pragma unroll
      for (int rg = 0; rg < 4; ++rg) csd[rg] = cse[rg];
    }
    __syncthreads();
    if (wid < 4 && !(wid & 1)) {
      f32x4 v = hred[wid >> 1][0][lane];
      cw[0] = v[0]; cw[1] = v[1]; cw[2] = v[2]; cw[3] = v[3];
    }
    __syncthreads();
  }

  // ================= sent_feat = sent_out @ W_feat^T + b_feat =================
  {
    const int ug = gw & 31;
    const int unit = ug * 16 + lr;
    const ushort* wb = P.wfeat + (size_t)(ug * 16 + lr) * H + lk;
#pragma unroll
    for (int it = 0; it < 5; ++it) {
      int mt = (gw + it * 128) >> 5;
      f32x4 acc = (f32x4)0.0f;
      const ushort* ab = P.sent_out_bf + (size_t)(mt * 16 + lr) * H + lk;
#pragma unroll
      for (int k0 = 0; k0 < H; k0 += 32) {
        bf16x8 a = ald_bf8(ab + k0);
        bf16x8 b = *reinterpret_cast<const bf16x8*>(wb + k0);
        acc = __builtin_amdgcn_mfma_f32_16x16x32_bf16(a, b, acc, 0, 0, 0);
      }
#pragma unroll
      for (int rg = 0; rg < 4; ++rg) {
        int row = mt * 16 + orow + rg;
        ast_f32(&P.sent_feat[(size_t)row * H + unit], acc[rg] + P.b_feat[unit]);
      }
    }
    fbar(P.flags, bid, UBLK, ++ph);
  }

  // ================= hierarchical decoder =================
  {
    const int half = wid & 1;            // k-half (wid<4)
    const int ug2 = bid * 2 + (wid >> 1);
    const int unit2 = ug2 * 16 + lr;
    const int ug = bid * 2 + wid;        // full-k layout (wid<2)
    const int unit = ug * 16 + lr;

    for (int n = 0; n < NN; ++n) {
      // pinned wd_Wh slice (immutable weights, normal loads)
      bf16x8 wreg[4][8];
      if (wid < 4) {
#pragma unroll
        for (int g = 0; g < 4; ++g)
#pragma unroll
          for (int kk = 0; kk < 8; ++kk)
            wreg[g][kk] = *reinterpret_cast<const bf16x8*>(
                P.wdWh + (size_t)g * H * H + (size_t)(ug2 * 16 + lr) * H +
                half * 256 + kk * 32 + lk);
      }
      // ---- 19 word-decoder LSTM steps ----
      for (int t = 0; t < TT - 1; ++t) {
        int stp = n * (TT - 1) + t;
        f32x4 acc[4];
        if (wid < 4) {
          const ushort* A = (t == 0)
              ? ((n == 0) ? P.sh0 : P.final_bf)
              : P.wh_bf + (size_t)(stp - 1) * 16 * H;
#pragma unroll
          for (int g = 0; g < 4; ++g) acc[g] = (f32x4)0.0f;
          const ushort* ab = A + (size_t)lr * H + half * 256 + lk;
#pragma unroll
          for (int kk = 0; kk < 8; ++kk) {
            bf16x8 a = ald_bf8(ab + kk * 32);
#pragma unroll
            for (int g = 0; g < 4; ++g)
              acc[g] = __builtin_amdgcn_mfma_f32_16x16x32_bf16(a, wreg[g][kk], acc[g], 0, 0, 0);
          }
          if (half) {
#pragma unroll
            for (int g = 0; g < 4; ++g) hred[wid >> 1][g][lane] = acc[g];
          }
        }
        __syncthreads();
        if (wid < 4 && !half) {
#pragma unroll
          for (int g = 0; g < 4; ++g) acc[g] += hred[wid >> 1][g][lane];
#pragma unroll
          for (int rg = 0; rg < 4; ++rg) {
            int row = orow + rg;
            const ushort* xi = P.XiD + (size_t)(stp * 16 + row) * 2048 + unit2;
            float gi = acc[0][rg] + b2f(xi[0]);
            float gf = acc[1][rg] + b2f(xi[512]);
            float gc = acc[2][rg] + b2f(xi[1024]);
            float go = acc[3][rg] + b2f(xi[1536]);
            float c = sigmoidf_(gf) * cw[rg] + sigmoidf_(gi) * tanhf(gc);
            float h = sigmoidf_(go) * tanhf(c);
            cw[rg] = c;
            ast_pair(P.wh_bf + (size_t)(stp * 16 + row) * H + (unit2 & ~1),
                     f2b_rne(h), lane);
          }
        }
        fbar(P.flags, bid, UBLK, ++ph);
      }
      // ---- sentence-decoder LSTM step ----
      if (wid < 2) {
        f32x4 acc[4];
#pragma unroll
        for (int g = 0; g < 4; ++g) acc[g] = (f32x4)0.0f;
        const ushort* A1 = P.wh_bf + (size_t)(n * (TT - 1) + TT - 2) * 16 * H;
        const ushort* A2 = (n == 0) ? P.sh0 : P.final_bf;
        const ushort* ab1 = A1 + (size_t)lr * H + lk;
        const ushort* wb1 = P.sdWi + (size_t)(ug * 16 + lr) * H + lk;
#pragma unroll
        for (int k0 = 0; k0 < H; k0 += 32) {
          bf16x8 a = ald_bf8(ab1 + k0);
#pragma unroll
          for (int g = 0; g < 4; ++g) {
            bf16x8 b = *reinterpret_cast<const bf16x8*>(wb1 + (size_t)g * H * H + k0);
            acc[g] = __builtin_amdgcn_mfma_f32_16x16x32_bf16(a, b, acc[g], 0, 0, 0);
          }
        }
        const ushort* ab2 = A2 + (size_t)lr * H + lk;
        const ushort* wb2 = P.sdWh + (size_t)(ug * 16 + lr) * H + lk;
#pragma unroll
        for (int k0 = 0; k0 < H; k0 += 32) {
          bf16x8 a = ald_bf8(ab2 + k0);
#pragma unroll
          for (int g = 0; g < 4; ++g) {
            bf16x8 b = *reinterpret_cast<const bf16x8*>(wb2 + (size_t)g * H * H + k0);
            acc[g] = __builtin_amdgcn_mfma_f32_16x16x32_bf16(a, b, acc[g], 0, 0, 0);
          }
        }
#pragma unroll
        for (int rg = 0; rg < 4; ++rg) {
          int row = orow + rg;
          float gi = acc[0][rg] + P.sd_b[0 * H + unit];
          float gf = acc[1][rg] + P.sd_b[1 * H + unit];
          float gc = acc[2][rg] + P.sd_b[2 * H + unit];
          float go = acc[3][rg] + P.sd_b[3 * H + unit];
          float c = sigmoidf_(gf) * csd[rg] + sigmoidf_(gi) * tanhf(gc);
          float h = sigmoidf_(go) * tanhf(c);
          csd[rg] = c;
          ast_pair(P.sdh_bf + (size_t)row * H + (unit & ~1), f2b_rne(h), lane);
        }
      }
      fbar(P.flags, bid, UBLK, ++ph);
      // ---- qb = sdh @ attn_Wh^T ----
      if (wid < 2) {
        f32x4 acc = (f32x4)0.0f;
        const ushort* ab = P.sdh_bf + (size_t)lr * H + lk;
        const ushort* wb = P.attnWh + (size_t)(ug * 16 + lr) * H + lk;
#pragma unroll
        for (int k0 = 0; k0 < H; k0 += 32) {
          bf16x8 a = ald_bf8(ab + k0);
          bf16x8 b = *reinterpret_cast<const bf16x8*>(wb + k0);
          acc = __builtin_amdgcn_mfma_f32_16x16x32_bf16(a, b, acc, 0, 0, 0);
        }
#pragma unroll
        for (int rg = 0; rg < 4; ++rg)
          ast_f32(&P.qb[(size_t)(orow + rg) * H + unit], acc[rg]);
      }
      fbar(P.flags, bid, UBLK, ++ph);
      // ---- e[s,b] ----
      for (int sb = gw; sb < 320; sb += 128) {
        int b = sb & 15;
        float cov = ald_f32(&P.covb[sb]);
        float sum = 0.f;
        for (int h2 = lane; h2 < H; h2 += 64)
          sum += tanhf(ald_f32(&P.sent_feat[(size_t)sb * H + h2]) +
                       ald_f32(&P.qb[b * H + h2]) +
                       cov * P.attn_wc[h2]) * P.attn_v[h2];
#pragma unroll
        for (int d = 1; d < 64; d <<= 1) sum += __shfl_xor(sum, d);
        if (lane == 0)
          ast_f32(&P.ebuf[sb], (P.articles[sb * LL] > 0) ? sum : -1e9f);
      }
      fbar(P.flags, bid, UBLK, ++ph);
      // ---- softmax over s + coverage loss + coverage update ----
      if (wid == 0) {
        int b = bid;
        float ev = (lane < SS) ? ald_f32(&P.ebuf[lane * 16 + b]) : -3.0e38f;
        float mx = ev;
#pragma unroll
        for (int d = 1; d < 64; d <<= 1) mx = fmaxf(mx, __shfl_xor(mx, d));
        float ex = (lane < SS) ? expf(ev - mx) : 0.f;
        float s = ex;
#pragma unroll
        for (int d = 1; d < 64; d <<= 1) s += __shfl_xor(s, d);
        float al = ex / s;
        float cl = 0.f;
        if (lane < SS) {
          int sb = lane * 16 + b;
          float cov = ald_f32(&P.covb[sb]);
          cl = fminf(al, cov);
          ast_f32(&P.covb[sb], cov + al);
          ast_f32(&P.alignb[sb], al);
        }
#pragma unroll
        for (int d = 1; d < 64; d <<= 1) cl += __shfl_xor(cl, d);
        if (lane == 0) atomicAdd(P.loss, cl * (1.f / BB));
      }
      fbar(P.flags, bid, UBLK, ++ph);
      // ---- context + catb = [ctx | sdh] (bf16, coherence-point) ----
      {
        int idx = bid * 512 + tid;
        int b = idx >> 9, h2 = idx & 511;
        float s = 0.f;
#pragma unroll
        for (int ss2 = 0; ss2 < SS; ++ss2)
          s += ald_f32(&P.alignb[ss2 * 16 + b]) *
               ald_f32(&P.sent_out[(size_t)(ss2 * 16 + b) * H + h2]);
        ushort sv = f2b_rne(s);
        uint other = __shfl_xor((uint)sv, 1);
        if (!(lane & 1)) {
          ast_u32((uint*)(P.catb + (size_t)b * 1024 + h2), (uint)sv | (other << 16));
          uint sd2 = ald_u32((const uint*)(P.sdh_bf + (size_t)b * H + h2));
          ast_u32((uint*)(P.catb + (size_t)b * 1024 + 512 + h2), sd2);
        }
      }
      fbar(P.flags, bid, UBLK, ++ph);
      // ---- final = tanh(catb @ W_out^T + b_out) ----
      if (wid < 2) {
        f32x4 acc = (f32x4)0.0f;
        const ushort* ab = P.catb + (size_t)lr * 1024 + lk;
        const ushort* wb = P.Wout + (size_t)(ug * 16 + lr) * 1024 + lk;
#pragma unroll
        for (int k0 = 0; k0 < 1024; k0 += 32) {
          bf16x8 a = ald_bf8(ab + k0);
          bf16x8 b = *reinterpret_cast<const bf16x8*>(wb + k0);
          acc = __builtin_amdgcn_mfma_f32_16x16x32_bf16(a, b, acc, 0, 0, 0);
        }
#pragma unroll
        for (int rg = 0; rg < 4; ++rg) {
          int row = orow + rg;
          float v = tanhf(acc[rg] + P.b_out[unit]);
          ast_pair(P.final_bf + (size_t)row * H + (unit & ~1), f2b_rne(v), lane);
        }
      }
      fbar(P.flags, bid, UBLK, ++ph);
    }
  }
}

// ---------------------------------------------------------------------------
// vocab: phase0 converts W_vocab f32->bf16 (full grid), fenced barrier, then
// A-register-pinned GEMM with per-XCD W chunk + fused (max,sumexp) epilogue.
// ---------------------------------------------------------------------------
__global__ __launch_bounds__(512) void vocab_kernel(
    const ushort* __restrict__ A, const float* __restrict__ Wf,
    ushort* __restrict__ Wbf, const float* __restrict__ bias,
    float* __restrict__ partials, uint* bcnt, uint* bgen)
{
  {
    int t0 = blockIdx.x * 512 + threadIdx.x;
    const int n4 = VT * H / 4;
    for (int i = t0; i < n4; i += VBLK * 512) {
      float4 v = reinterpret_cast<const float4*>(Wf)[i];
      ushort4 o;
      o.x = f2b_rne(v.x); o.y = f2b_rne(v.y);
      o.z = f2b_rne(v.z); o.w = f2b_rne(v.w);
      reinterpret_cast<ushort4*>(Wbf)[i] = o;
    }
  }
  gbar(bcnt, bgen, VBLK);

  __shared__ float red[4][64][2];
  const int bid = blockIdx.x;
  const int chunk = bid & 7, mt = bid >> 3;
  const int tid = threadIdx.x;
  const int wid = tid >> 6, lane = tid & 63;
  const int wm = wid >> 2, wn = wid & 3;
  const int m0 = mt * 64 + wm * 32;
  const int lr = lane & 15;
  const int lk = (lane >> 4) << 3;

  bf16x8 areg[2][16];
#pragma unroll
  for (int i = 0; i < 2; ++i)
#pragma unroll
    for (int kk = 0; kk < 16; ++kk)
      areg[i][kk] = *reinterpret_cast<const bf16x8*>(
          A + (size_t)(m0 + i * 16 + lr) * H + kk * 32 + lk);

  for (int nt2 = 0; nt2 < 15; ++nt2) {
    const int n0 = chunk * 3840 + nt2 * 256 + wn * 64;
    f32x4 acc[2][4];
#pragma unroll
    for (int i = 0; i < 2; ++i)
#pragma unroll
      for (int nf = 0; nf < 4; ++nf) acc[i][nf] = (f32x4)0.0f;

#pragma unroll 4
    for (int kk = 0; kk < 16; ++kk) {
      bf16x8 b[4];
#pragma unroll
      for (int nf = 0; nf < 4; ++nf) {
        int n = n0 + nf * 16 + lr;
        bf16x8 bz = (bf16x8)(short)0;
        if (n < VT) bz = *reinterpret_cast<const bf16x8*>(Wbf + (size_t)n * H + kk * 32 + lk);
        b[nf] = bz;
      }
#pragma unroll
      for (int i = 0; i < 2; ++i)
#pragma unroll
        for (int nf = 0; nf < 4; ++nf)
          acc[i][nf] = __builtin_amdgcn_mfma_f32_16x16x32_bf16(areg[i][kk], b[nf], acc[i][nf], 0, 0, 0);
    }

    float bc[4];
    int val[4];
#pragma unroll
    for (int nf = 0; nf < 4; ++nf) {
      int n = n0 + nf * 16 + lr;
      val[nf] = (n < VT);
      bc[nf] = val[nf] ? bias[n] : 0.f;
    }
#pragma unroll
    for (int i = 0; i < 2; ++i) {
#pragma unroll
      for (int jreg = 0; jreg < 4; ++jreg) {
        float lg[4];
        float mx = -3.0e38f;
#pragma unroll
        for (int nf = 0; nf < 4; ++nf) {
          lg[nf] = val[nf] ? (acc[i][nf][jreg] + bc[nf]) : -3.0e38f;
          mx = fmaxf(mx, lg[nf]);
        }
#pragma unroll
        for (int d = 1; d < 16; d <<= 1) mx = fmaxf(mx, __shfl_xor(mx, d));
        float s = 0.f;
#pragma unroll
        for (int nf = 0; nf < 4; ++nf) s += val[nf] ? expf(lg[nf] - mx) : 0.f;
#pragma unroll
        for (int d = 1; d < 16; d <<= 1) s += __shfl_xor(s, d);
        if (lr == 0) {
          int rloc = wm * 32 + i * 16 + (lane >> 4) * 4 + jreg;
          red[wn][rloc][0] = mx;
          red[wn][rloc][1] = s;
        }
      }
    }
    __syncthreads();
    if (tid < 64) {
      int r2 = tid;
      float M = -3.0e38f;
#pragma unroll
      for (int w = 0; w < 4; ++w) M = fmaxf(M, red[w][r2][0]);
      float S = 0.f;
#pragma unroll
      for (int w = 0; w < 4; ++w) S += red[w][r2][1] * expf(red[w][r2][0] - M);
      size_t p = ((size_t)(mt * 64 + r2) * NT2 + chunk * 15 + nt2) * 2;
      partials[p] = M;
      partials[p + 1] = S;
    }
    __syncthreads();
  }
}

// target logit per decoder row (consistent bf16 operands)
__global__ void tlog_kernel(const ushort* __restrict__ wh_bf,
                            const ushort* __restrict__ Wv_bf,
                            const float* __restrict__ bv,
                            const int* __restrict__ summaries,
                            float* __restrict__ tlog)
{
  int row = blockIdx.x;
  int lane = threadIdx.x;
  int b = row & 15, stp = row >> 4;
  int n = stp / (TT - 1), t = stp % (TT - 1);
  int tgt = summaries[(n * BB + b) * TT + t + 1];
  float s = 0.f;
  for (int k = lane; k < H; k += 64)
    s += b2f(wh_bf[(size_t)row * H + k]) * b2f(Wv_bf[(size_t)tgt * H + k]);
#pragma unroll
  for (int d = 1; d < 64; d <<= 1) s += __shfl_xor(s, d);
  if (lane == 0) tlog[row] = s + bv[tgt];
}

// per-step masked-mean NLL from partials
__global__ __launch_bounds__(256) void nll_kernel(
    const float* __restrict__ partials, const float* __restrict__ tlog,
    const int* __restrict__ summaries, float* __restrict__ loss)
{
  int stp = blockIdx.x;
  int tid = threadIdx.x;
  int rr = tid >> 4, ch = tid & 15;
  int row = stp * 16 + rr;
  const float* pr = partials + (size_t)row * NT2 * 2;
  float mx = -3.0e38f;
  for (int t2 = ch; t2 < NT2; t2 += 16) mx = fmaxf(mx, pr[t2 * 2]);
#pragma unroll
  for (int d = 1; d < 16; d <<= 1) mx = fmaxf(mx, __shfl_xor(mx, d));
  float s = 0.f;
  for (int t2 = ch; t2 < NT2; t2 += 16) s += pr[t2 * 2 + 1] * expf(pr[t2 * 2] - mx);
#pragma unroll
  for (int d = 1; d < 16; d <<= 1) s += __shfl_xor(s, d);
  __shared__ float sh_n[16], sh_m[16];
  if (ch == 0) {
    float lse = mx + logf(s);
    float nll = lse - tlog[row];
    int b = row & 15;
    int n = stp / (TT - 1), t = stp % (TT - 1);
    int wa = summaries[(n * BB + b) * TT + t + 1];
    sh_n[rr] = (wa != 0) ? nll : 0.f;
    sh_m[rr] = (wa != 0) ? 1.f : 0.f;
  }
  __syncthreads();
  if (tid == 0) {
    float sn = 0.f, sm = 0.f;
    for (int r2 = 0; r2 < 16; ++r2) { sn += sh_n[r2]; sm += sh_m[r2]; }
    atomicAdd(loss, sn / fmaxf(sm, 1.f));
  }
}

// ---------------------------------------------------------------------------
extern "C" void kernel_launch(void* const* d_in, const int* in_sizes, int n_in,
                              void* d_out, int out_size, void* d_ws, size_t ws_size,
                              hipStream_t stream)
{
  (void)in_sizes; (void)n_in; (void)out_size; (void)ws_size;
  const int*   articles  = (const int*)d_in[0];
  const int*   summaries = (const int*)d_in[1];
  const float* emb_src   = (const float*)d_in[2];
  const float* emb_tgt   = (const float*)d_in[3];
  const float* we_Wi = (const float*)d_in[4];
  const float* we_Wh = (const float*)d_in[5];
  const float* we_b  = (const float*)d_in[6];
  const float* se_Wi = (const float*)d_in[7];
  const float* se_Wh = (const float*)d_in[8];
  const float* se_b  = (const float*)d_in[9];
  const float* W_feat = (const float*)d_in[10];
  const float* b_feat = (const float*)d_in[11];
  const float* wd_Wi = (const float*)d_in[12];
  const float* wd_Wh = (const float*)d_in[13];
  const float* wd_b  = (const float*)d_in[14];
  const float* W_vocab = (const float*)d_in[15];
  const float* b_vocab = (const float*)d_in[16];
  const float* sd_Wi = (const float*)d_in[17];
  const float* sd_Wh = (const float*)d_in[18];
  const float* sd_b  = (const float*)d_in[19];
  const float* attn_Wh = (const float*)d_in[20];
  const float* attn_wc = (const float*)d_in[21];
  const float* attn_v  = (const float*)d_in[22];
  const float* W_out = (const float*)d_in[23];
  const float* b_out = (const float*)d_in[24];

  char* wsb = (char*)d_ws;
  size_t off = 0;
  auto alloc = [&](size_t bytes) -> char* {
    char* p = wsb + off;
    off += (bytes + 255) & ~(size_t)255;
    return p;
  };

  // regA: A_we (prep->proj) UNION {wh_bf, partials, tlog} (uni onwards)
  char* regA = alloc(9830400);
  ushort* A_we     = (ushort*)regA;
  ushort* wh_bf    = (ushort*)regA;                    // 1856*512*2 = 1,900,544
  float*  partials = (float*)(regA + 1900544);         // 1856*120*2*4 = 1,781,760
  float*  tlogb    = (float*)(regA + 3682304);         // 1824*4

  ushort* A_wd = (ushort*)alloc((size_t)MROWS * H * 2);

  // regW: XiW bf16 (proj->uni word-enc) UNION Wv_bf (vocab)
  char* regW = alloc((size_t)9600 * 2048 * 2);
  ushort* XiW   = (ushort*)regW;
  ushort* Wv_bf = (ushort*)regW;

  ushort* XiD = (ushort*)alloc((size_t)MROWS * 2048 * 2);

  ushort* weWi  = (ushort*)alloc(4 * H * H * 2);
  ushort* wdWi  = (ushort*)alloc(4 * H * H * 2);
  ushort* weWh  = (ushort*)alloc(4 * H * H * 2);
  ushort* seWi  = (ushort*)alloc(4 * H * H * 2);
  ushort* seWh  = (ushort*)alloc(4 * H * H * 2);
  ushort* wdWh  = (ushort*)alloc(4 * H * H * 2);
  ushort* sdWi  = (ushort*)alloc(4 * H * H * 2);
  ushort* sdWh  = (ushort*)alloc(4 * H * H * 2);
  ushort* wfeat = (ushort*)alloc(H * H * 2);
  ushort* attnWh= (ushort*)alloc(H * H * 2);
  ushort* Wout  = (ushort*)alloc(H * 2 * H * 2);

  float*  XiS = (float*)alloc((size_t)320 * 2048 * 4);
  ushort* h0  = (ushort*)alloc(320 * H * 2);
  ushort* h1  = (ushort*)alloc(320 * H * 2);
  ushort* sh0 = (ushort*)alloc(16 * H * 2);
  ushort* sh1 = (ushort*)alloc(16 * H * 2);
  float*  sent_out    = (float*)alloc(320 * H * 4);
  ushort* sent_out_bf = (ushort*)alloc(320 * H * 2);
  float*  sent_feat   = (float*)alloc(320 * H * 4);
  ushort* sdh_bf   = (ushort*)alloc(16 * H * 2);
  ushort* final_bf = (ushort*)alloc(16 * H * 2);
  ushort* catb     = (ushort*)alloc(16 * 1024 * 2);
  float*  qb       = (float*)alloc(16 * H * 4);
  float*  ebuf   = (float*)alloc(1280);
  float*  alignb = (float*)alloc(1280);
  float*  covb   = (float*)alloc(1280);
  uint*   bar    = (uint*)alloc(256);            // vocab fenced barrier
  uint*   flags  = (uint*)alloc(UBLK * 16 * 4);  // uni flag barrier

  float* loss = (float*)d_out;
  hipMemsetAsync(loss, 0, 4, stream);
  hipMemsetAsync(covb, 0, 1280, stream);
  hipMemsetAsync(h0, 0, 320 * H * 2, stream);
  hipMemsetAsync(sh0, 0, 16 * H * 2, stream);
  hipMemsetAsync(bar, 0, 256, stream);
  hipMemsetAsync(flags, 0, UBLK * 16 * 4, stream);

  // 1) prep: gathers + weight conversions
  {
    PrepP P = {articles, summaries, emb_src, emb_tgt,
               we_Wi, wd_Wi, we_Wh, se_Wi, se_Wh, W_feat,
               wd_Wh, sd_Wi, sd_Wh, attn_Wh, W_out,
               A_we, A_wd, weWi, wdWi, weWh, seWi, seWh, wfeat,
               wdWh, sdWi, sdWh, attnWh, Wout};
    prep_kernel<<<2048, 256, 0, stream>>>(P);
  }

  // 2) input projections
  proj_mfma_kernel<<<1432, 512, 0, stream>>>(A_we, weWi, we_b, XiW,
                                             A_wd, wdWi, wd_b, XiD);

  // zero wh_bf pad rows (A_we dead after proj; stream-ordered)
  hipMemsetAsync((char*)wh_bf + (size_t)MROWS * H * 2, 0,
                 (size_t)(MPAD - MROWS) * H * 2, stream);

  // 3) unified sequential kernel (16 blocks, fence-free flag barrier)
  {
    UP P;
    P.XiW = XiW; P.XiD = XiD;
    P.weWh = weWh; P.seWi = seWi; P.seWh = seWh; P.wfeat = wfeat;
    P.wdWh = wdWh; P.sdWi = sdWi; P.sdWh = sdWh; P.attnWh = attnWh; P.Wout = Wout;
    P.se_b = se_b; P.b_feat = b_feat; P.sd_b = sd_b; P.b_out = b_out;
    P.attn_wc = attn_wc; P.attn_v = attn_v; P.articles = articles;
    P.h0 = h0; P.h1 = h1; P.XiS = XiS; P.sh0 = sh0; P.sh1 = sh1;
    P.sent_out = sent_out; P.sent_out_bf = sent_out_bf; P.sent_feat = sent_feat;
    P.wh_bf = wh_bf; P.sdh_bf = sdh_bf; P.final_bf = final_bf; P.catb = catb;
    P.qb = qb; P.ebuf = ebuf; P.alignb = alignb; P.covb = covb; P.loss = loss;
    P.flags = flags;
    uni_kernel<<<UBLK, 512, 0, stream>>>(P);
  }

  // 4) vocab (conversion + GEMM + partial softmax) + NLL
  vocab_kernel<<<VBLK, 512, 0, stream>>>(wh_bf, W_vocab, Wv_bf, b_vocab,
                                         partials, bar, bar + 1);
  tlog_kernel<<<MROWS, 64, 0, stream>>>(wh_bf, Wv_bf, b_vocab, summaries, tlogb);
  nll_kernel<<<NSTEPS, 256, 0, stream>>>(partials, tlogb, summaries, loss);
}

// Round 7
// 5032.494 us; speedup vs baseline: 1.1379x; 1.1379x over previous
//
#include <hip/hip_runtime.h>
#include <cstdint>
#include <cstddef>

#define H 512
#define SS 20
#define BB 16
#define LL 30
#define NN 6
#define TT 20
#define VT 30000
#define MROWS 1824   /* N*B*(T-1) */
#define NSTEPS 114   /* N*(T-1) */
#define MPAD 1856    /* 29*64 */
#define NT2 120      /* 8 chunks * 15 tiles of 256 */
#define UBLK 16      /* sequential-role blocks */
#define NV 232       /* vocab-role blocks = 29 mt * 8 chunks */
#define MEGA 248     /* UBLK + NV */

#define SCOPE_AGENT __HIP_MEMORY_SCOPE_AGENT

typedef __attribute__((ext_vector_type(8))) short bf16x8;
typedef __attribute__((ext_vector_type(4))) float f32x4;

__device__ __forceinline__ float sigmoidf_(float x) { return 1.f / (1.f + expf(-x)); }
__device__ __forceinline__ float b2f(ushort u) { return __uint_as_float(((uint32_t)u) << 16); }
__device__ __forceinline__ ushort f2b_rne(float f) {
  uint32_t u = __float_as_uint(f);
  return (ushort)((u + 0x7fffu + ((u >> 16) & 1u)) >> 16);
}

__device__ __forceinline__ void ast_u32(uint* p, uint v) {
  __hip_atomic_store(p, v, __ATOMIC_RELAXED, SCOPE_AGENT);
}
__device__ __forceinline__ uint ald_u32(const uint* p) {
  return __hip_atomic_load(p, __ATOMIC_RELAXED, SCOPE_AGENT);
}

// ---------------------------------------------------------------------------
// grid barrier, fence-minimal: relaxed-poll per-block flags; exactly one
// agent release fence (L2 writeback) at arrival and one acquire fence
// (L1/L2 invalidate) after all blocks arrived. Data uses normal ld/st.
// ---------------------------------------------------------------------------
__device__ __forceinline__ void sbar(uint* flags, int slot, int nblk, uint phase)
{
  __syncthreads();
  if (threadIdx.x == 0) {
    __builtin_amdgcn_fence(__ATOMIC_RELEASE, "agent");   // wb dirty L2 once
    ast_u32(&flags[slot * 16], phase);
  }
  if ((int)threadIdx.x < nblk) {
    while (ald_u32(&flags[threadIdx.x * 16]) < phase)
      __builtin_amdgcn_s_sleep(1);
  }
  __syncthreads();
  if (threadIdx.x == 0)
    __builtin_amdgcn_fence(__ATOMIC_ACQUIRE, "agent");   // inv L1+L2 once
  __syncthreads();
}

// ---------------------------------------------------------------------------
// prep: token gathers -> bf16 A matrices; weight matrices f32 -> bf16
// ---------------------------------------------------------------------------
struct PrepP {
  const int* articles; const int* summaries;
  const float* emb_src; const float* emb_tgt;
  const float* we_Wi; const float* wd_Wi; const float* we_Wh;
  const float* se_Wi; const float* se_Wh; const float* W_feat;
  const float* wd_Wh; const float* sd_Wi; const float* sd_Wh;
  const float* attn_Wh; const float* W_out;
  ushort* A_we; ushort* A_wd;
  ushort* weWi; ushort* wdWi; ushort* weWh;
  ushort* seWi; ushort* seWh; ushort* wfeat;
  ushort* wdWh; ushort* sdWi; ushort* sdWh;
  ushort* attnWh; ushort* Wout;
};

__device__ __forceinline__ void conv_f2b(const float* __restrict__ src,
                                         ushort* __restrict__ dst, int n4,
                                         int t0, int stride)
{
  for (int i = t0; i < n4; i += stride) {
    float4 v = reinterpret_cast<const float4*>(src)[i];
    ushort4 o;
    o.x = f2b_rne(v.x); o.y = f2b_rne(v.y);
    o.z = f2b_rne(v.z); o.w = f2b_rne(v.w);
    reinterpret_cast<ushort4*>(dst)[i] = o;
  }
}

__global__ __launch_bounds__(256) void prep_kernel(PrepP P)
{
  const int t0 = blockIdx.x * 256 + threadIdx.x;
  const int stride = gridDim.x * 256;
  for (int i = t0; i < SS * BB * LL * H; i += stride) {
    int m = i >> 9, k = i & 511;
    int l = m / (SS * BB), sb = m % (SS * BB);
    int tok = P.articles[sb * LL + l];
    P.A_we[i] = f2b_rne(P.emb_src[(size_t)tok * H + k]);
  }
  for (int i = t0; i < MROWS * H; i += stride) {
    int m = i >> 9, k = i & 511;
    int stp = m >> 4, b = m & 15;
    int n = stp / (TT - 1), t = stp % (TT - 1);
    int tok = P.summaries[(n * BB + b) * TT + t];
    P.A_wd[i] = f2b_rne(P.emb_tgt[(size_t)tok * H + k]);
  }
  const int Q = 4 * H * H / 4;
  conv_f2b(P.we_Wi, P.weWi, Q, t0, stride);
  conv_f2b(P.wd_Wi, P.wdWi, Q, t0, stride);
  conv_f2b(P.we_Wh, P.weWh, Q, t0, stride);
  conv_f2b(P.se_Wi, P.seWi, Q, t0, stride);
  conv_f2b(P.se_Wh, P.seWh, Q, t0, stride);
  conv_f2b(P.wd_Wh, P.wdWh, Q, t0, stride);
  conv_f2b(P.sd_Wi, P.sdWi, Q, t0, stride);
  conv_f2b(P.sd_Wh, P.sdWh, Q, t0, stride);
  conv_f2b(P.W_feat, P.wfeat, H * H / 4, t0, stride);
  conv_f2b(P.attn_Wh, P.attnWh, H * H / 4, t0, stride);
  conv_f2b(P.W_out, P.Wout, H * 2 * H / 4, t0, stride);
}

// ---------------------------------------------------------------------------
// bf16 MFMA input projections: Xi = A @ Wi^T + b  (bf16 out, [M][2048])
// ---------------------------------------------------------------------------
__global__ __launch_bounds__(512) void proj_mfma_kernel(
    const ushort* __restrict__ A_we, const ushort* __restrict__ weWi,
    const float* __restrict__ we_b, ushort* __restrict__ XiW,
    const ushort* __restrict__ A_wd, const ushort* __restrict__ wdWi,
    const float* __restrict__ wd_b, ushort* __restrict__ XiD)
{
  int bid = blockIdx.x;
  const ushort* A; const ushort* W; const float* bias; ushort* C; int M, mt, nt;
  if (bid < 1200) { A = A_we; W = weWi; bias = we_b; C = XiW; M = 9600; mt = bid >> 3; nt = bid & 7; }
  else { int b2 = bid - 1200; A = A_wd; W = wdWi; bias = wd_b; C = XiD; M = MROWS; mt = b2 >> 3; nt = b2 & 7; }
  const int tid = threadIdx.x, wid = tid >> 6, lane = tid & 63;
  const int wm = wid >> 2, wn = wid & 3;
  const int m0 = mt * 64 + wm * 32, n0 = nt * 256 + wn * 64;
  const int lr = lane & 15, lk = (lane >> 4) << 3;

  f32x4 acc[2][4];
#pragma unroll
  for (int i = 0; i < 2; ++i)
#pragma unroll
    for (int nf = 0; nf < 4; ++nf) acc[i][nf] = (f32x4)0.0f;

  for (int k0 = 0; k0 < H; k0 += 32) {
    bf16x8 a[2], b[4];
#pragma unroll
    for (int i = 0; i < 2; ++i) {
      int m = m0 + i * 16 + lr;
      bf16x8 az = (bf16x8)(short)0;
      if (m < M) az = *reinterpret_cast<const bf16x8*>(A + (size_t)m * H + k0 + lk);
      a[i] = az;
    }
#pragma unroll
    for (int nf = 0; nf < 4; ++nf)
      b[nf] = *reinterpret_cast<const bf16x8*>(W + (size_t)(n0 + nf * 16 + lr) * H + k0 + lk);
#pragma unroll
    for (int i = 0; i < 2; ++i)
#pragma unroll
      for (int nf = 0; nf < 4; ++nf)
        acc[i][nf] = __builtin_amdgcn_mfma_f32_16x16x32_bf16(a[i], b[nf], acc[i][nf], 0, 0, 0);
  }
#pragma unroll
  for (int i = 0; i < 2; ++i)
#pragma unroll
    for (int nf = 0; nf < 4; ++nf) {
      int n = n0 + nf * 16 + lr;
      float bv = bias[n];
#pragma unroll
      for (int jreg = 0; jreg < 4; ++jreg) {
        int row = m0 + i * 16 + (lane >> 4) * 4 + jreg;
        if (row < M) C[(size_t)row * 2048 + n] = f2b_rne(acc[i][nf][jreg] + bv);
      }
    }
}

// ---------------------------------------------------------------------------
// MEGA kernel: blocks 0..15 = sequential chain (word-enc + sent-enc + decoder)
//              blocks 16..247 = vocab pipeline (Wv f2b + per-sentence partials)
// Producer->consumer via monotone vflag: 1 = XiW dead; 2+n = sentence n ready.
// ---------------------------------------------------------------------------
struct MP {
  const ushort* XiW; const ushort* XiD;
  const ushort* weWh; const ushort* seWi; const ushort* seWh;
  const ushort* wfeat; const ushort* wdWh; const ushort* sdWi;
  const ushort* sdWh; const ushort* attnWh; const ushort* Wout;
  const float* se_b; const float* b_feat; const float* sd_b; const float* b_out;
  const float* attn_wc; const float* attn_v; const int* articles;
  ushort* h0; ushort* h1;
  float* XiS;
  ushort* sh0; ushort* sh1;
  float* sent_out; ushort* sent_out_bf; float* sent_feat;
  ushort* wh_bf; ushort* sdh_bf; ushort* final_bf; ushort* catb;
  float* qb; float* ebuf; float* alignb; float* covb; float* loss;
  uint* sflags;       // UBLK barrier flags
  uint* vbflags;      // NV barrier flags
  uint* vflag;        // producer->consumer progress
  const float* Wv; ushort* Wv_bf; const float* bv; float* partials;
};

__global__ __launch_bounds__(512) void mega_kernel(MP P)
{
  const int tid = threadIdx.x, bid = blockIdx.x;
  const int wid = tid >> 6, lane = tid & 63;
  const int lr = lane & 15;
  const int lk = (lane >> 4) << 3;
  const int orow = (lane >> 4) << 2;

  if (bid >= UBLK) {
    // ================= VOCAB ROLE =================
    const int v = bid - UBLK;            // 0..231
    const int mt = v >> 3, chunk = v & 7;
    __shared__ float red[4][64][2];

    // wait until XiW is dead (word encoder + XiS done), then convert W_vocab
    if (tid == 0) {
      while (ald_u32(P.vflag) < 1u) __builtin_amdgcn_s_sleep(16);
    }
    __syncthreads();
    {
      const int n4 = VT * H / 4;
      for (int i = v * 512 + tid; i < n4; i += NV * 512) {
        float4 w = reinterpret_cast<const float4*>(P.Wv)[i];
        ushort4 o;
        o.x = f2b_rne(w.x); o.y = f2b_rne(w.y);
        o.z = f2b_rne(w.z); o.w = f2b_rne(w.w);
        reinterpret_cast<ushort4*>(P.Wv_bf)[i] = o;
      }
    }
    sbar(P.vbflags, v, NV, 1u);          // all Wv_bf visible to all V blocks

    // wait for the sentence containing this row tile, then fence once
    {
      int lastStep = mt * 4 + 3; if (lastStep > 113) lastStep = 113;
      uint want = 2u + (uint)(lastStep / 19);
      if (tid == 0) {
        while (ald_u32(P.vflag) < want) __builtin_amdgcn_s_sleep(16);
        __builtin_amdgcn_fence(__ATOMIC_ACQUIRE, "agent");
      }
      __syncthreads();
    }

    const int wm = wid >> 2, wn = wid & 3;
    const int m0 = mt * 64 + wm * 32;
    bf16x8 areg[2][16];
#pragma unroll
    for (int i = 0; i < 2; ++i)
#pragma unroll
      for (int kk = 0; kk < 16; ++kk)
        areg[i][kk] = *reinterpret_cast<const bf16x8*>(
            P.wh_bf + (size_t)(m0 + i * 16 + lr) * H + kk * 32 + lk);

    for (int nt2 = 0; nt2 < 15; ++nt2) {
      const int n0 = chunk * 3840 + nt2 * 256 + wn * 64;
      f32x4 acc[2][4];
#pragma unroll
      for (int i = 0; i < 2; ++i)
#pragma unroll
        for (int nf = 0; nf < 4; ++nf) acc[i][nf] = (f32x4)0.0f;

#pragma unroll 4
      for (int kk = 0; kk < 16; ++kk) {
        bf16x8 b[4];
#pragma unroll
        for (int nf = 0; nf < 4; ++nf) {
          int n = n0 + nf * 16 + lr;
          bf16x8 bz = (bf16x8)(short)0;
          if (n < VT) bz = *reinterpret_cast<const bf16x8*>(P.Wv_bf + (size_t)n * H + kk * 32 + lk);
          b[nf] = bz;
        }
#pragma unroll
        for (int i = 0; i < 2; ++i)
#pragma unroll
          for (int nf = 0; nf < 4; ++nf)
            acc[i][nf] = __builtin_amdgcn_mfma_f32_16x16x32_bf16(areg[i][kk], b[nf], acc[i][nf], 0, 0, 0);
      }

      float bc[4];
      int val[4];
#pragma unroll
      for (int nf = 0; nf < 4; ++nf) {
        int n = n0 + nf * 16 + lr;
        val[nf] = (n < VT);
        bc[nf] = val[nf] ? P.bv[n] : 0.f;
      }
#pragma unroll
      for (int i = 0; i < 2; ++i) {
#pragma unroll
        for (int jreg = 0; jreg < 4; ++jreg) {
          float lg[4];
          float mx = -3.0e38f;
#pragma unroll
          for (int nf = 0; nf < 4; ++nf) {
            lg[nf] = val[nf] ? (acc[i][nf][jreg] + bc[nf]) : -3.0e38f;
            mx = fmaxf(mx, lg[nf]);
          }
#pragma unroll
          for (int d = 1; d < 16; d <<= 1) mx = fmaxf(mx, __shfl_xor(mx, d));
          float s = 0.f;
#pragma unroll
          for (int nf = 0; nf < 4; ++nf) s += val[nf] ? expf(lg[nf] - mx) : 0.f;
#pragma unroll
          for (int d = 1; d < 16; d <<= 1) s += __shfl_xor(s, d);
          if (lr == 0) {
            int rloc = wm * 32 + i * 16 + (lane >> 4) * 4 + jreg;
            red[wn][rloc][0] = mx;
            red[wn][rloc][1] = s;
          }
        }
      }
      __syncthreads();
      if (tid < 64) {
        int r2 = tid;
        float M = -3.0e38f;
#pragma unroll
        for (int w = 0; w < 4; ++w) M = fmaxf(M, red[w][r2][0]);
        float S = 0.f;
#pragma unroll
        for (int w = 0; w < 4; ++w) S += red[w][r2][1] * expf(red[w][r2][0] - M);
        size_t p = ((size_t)(mt * 64 + r2) * NT2 + chunk * 15 + nt2) * 2;
        P.partials[p] = M;
        P.partials[p + 1] = S;
      }
      __syncthreads();
    }
    return;
  }

  // ================= SEQUENTIAL ROLE (blocks 0..15) =================
  __shared__ f32x4 hred[2][4][64];
  const int gw = bid * 8 + wid;
  uint ph = 0;

  // ---- word encoder: 30 steps, M=320 ----
  {
    float cst[5][4];
#pragma unroll
    for (int it = 0; it < 5; ++it)
#pragma unroll
      for (int rg = 0; rg < 4; ++rg) cst[it][rg] = 0.f;
    ushort* cur = P.h0;
    ushort* nxt = P.h1;
    const int ug = gw & 31;
    const int unit = ug * 16 + lr;
    const ushort* wb = P.weWh + (size_t)(ug * 16 + lr) * H + lk;
    for (int l = 0; l < LL; ++l) {
#pragma unroll
      for (int it = 0; it < 5; ++it) {
        int mt = (gw + it * 128) >> 5;
        f32x4 acc[4];
#pragma unroll
        for (int g = 0; g < 4; ++g) acc[g] = (f32x4)0.0f;
        const ushort* ab = cur + (size_t)(mt * 16 + lr) * H + lk;
#pragma unroll
        for (int k0 = 0; k0 < H; k0 += 32) {
          bf16x8 a = *reinterpret_cast<const bf16x8*>(ab + k0);
#pragma unroll
          for (int g = 0; g < 4; ++g) {
            bf16x8 b = *reinterpret_cast<const bf16x8*>(wb + (size_t)g * H * H + k0);
            acc[g] = __builtin_amdgcn_mfma_f32_16x16x32_bf16(a, b, acc[g], 0, 0, 0);
          }
        }
#pragma unroll
        for (int rg = 0; rg < 4; ++rg) {
          int row = mt * 16 + orow + rg;
          const ushort* xi = P.XiW + (size_t)(l * 320 + row) * 2048 + unit;
          float gi = acc[0][rg] + b2f(xi[0]);
          float gf = acc[1][rg] + b2f(xi[512]);
          float gc = acc[2][rg] + b2f(xi[1024]);
          float go = acc[3][rg] + b2f(xi[1536]);
          float c = sigmoidf_(gf) * cst[it][rg] + sigmoidf_(gi) * tanhf(gc);
          float h = sigmoidf_(go) * tanhf(c);
          cst[it][rg] = c;
          nxt[(size_t)row * H + unit] = f2b_rne(h);
        }
      }
      sbar(P.sflags, bid, UBLK, ++ph);
      ushort* t = cur; cur = nxt; nxt = t;
    }
    // XiS = h30 @ se_Wi^T + se_b (f32)
    {
      const ushort* wbs = P.seWi + (size_t)(ug * 16 + lr) * H + lk;
#pragma unroll
      for (int it = 0; it < 5; ++it) {
        int mt = (gw + it * 128) >> 5;
        f32x4 acc[4];
#pragma unroll
        for (int g = 0; g < 4; ++g) acc[g] = (f32x4)0.0f;
        const ushort* ab = cur + (size_t)(mt * 16 + lr) * H + lk;
#pragma unroll
        for (int k0 = 0; k0 < H; k0 += 32) {
          bf16x8 a = *reinterpret_cast<const bf16x8*>(ab + k0);
#pragma unroll
          for (int g = 0; g < 4; ++g) {
            bf16x8 b = *reinterpret_cast<const bf16x8*>(wbs + (size_t)g * H * H + k0);
            acc[g] = __builtin_amdgcn_mfma_f32_16x16x32_bf16(a, b, acc[g], 0, 0, 0);
          }
        }
#pragma unroll
        for (int rg = 0; rg < 4; ++rg) {
          int row = mt * 16 + orow + rg;
#pragma unroll
          for (int g = 0; g < 4; ++g)
            P.XiS[(size_t)row * 2048 + g * H + unit] = acc[g][rg] + P.se_b[g * H + unit];
        }
      }
    }
    sbar(P.sflags, bid, UBLK, ++ph);
    // XiW is now dead -> release vocab conversion
    if (bid == 0 && tid == 0)
      __hip_atomic_store(P.vflag, 1u, __ATOMIC_RELEASE, SCOPE_AGENT);
  }

  // ---- sentence encoder: 20 steps, M=16 ----
  float cw[4] = {0.f, 0.f, 0.f, 0.f};
  float csd[4] = {0.f, 0.f, 0.f, 0.f};
  {
    float cse[4] = {0.f, 0.f, 0.f, 0.f};
    ushort* cur = P.sh0;
    ushort* nxt = P.sh1;
    const int ug = bid * 2 + wid;        // valid when wid<2
    const int unit = ug * 16 + lr;
    for (int s = 0; s < SS; ++s) {
      if (wid < 2) {
        f32x4 acc[4];
#pragma unroll
        for (int g = 0; g < 4; ++g) acc[g] = (f32x4)0.0f;
        const ushort* ab = cur + (size_t)lr * H + lk;
        const ushort* wb = P.seWh + (size_t)(ug * 16 + lr) * H + lk;
#pragma unroll
        for (int k0 = 0; k0 < H; k0 += 32) {
          bf16x8 a = *reinterpret_cast<const bf16x8*>(ab + k0);
#pragma unroll
          for (int g = 0; g < 4; ++g) {
            bf16x8 b = *reinterpret_cast<const bf16x8*>(wb + (size_t)g * H * H + k0);
            acc[g] = __builtin_amdgcn_mfma_f32_16x16x32_bf16(a, b, acc[g], 0, 0, 0);
          }
        }
#pragma unroll
        for (int rg = 0; rg < 4; ++rg) {
          int row = orow + rg;
          const float* xi = P.XiS + (size_t)(s * 16 + row) * 2048 + unit;
          float gi = acc[0][rg] + xi[0];
          float gf = acc[1][rg] + xi[512];
          float gc = acc[2][rg] + xi[1024];
          float go = acc[3][rg] + xi[1536];
          float c = sigmoidf_(gf) * cse[rg] + sigmoidf_(gi) * tanhf(gc);
          float h = sigmoidf_(go) * tanhf(c);
          cse[rg] = c;
          nxt[(size_t)row * H + unit] = f2b_rne(h);
          P.sent_out[(size_t)(s * 16 + row) * H + unit] = h;
          P.sent_out_bf[(size_t)(s * 16 + row) * H + unit] = f2b_rne(h);
        }
      }
      sbar(P.sflags, bid, UBLK, ++ph);
      ushort* t = cur; cur = nxt; nxt = t;
    }
    if (wid < 2) {
      f32x4 v; v[0] = cse[0]; v[1] = cse[1]; v[2] = cse[2]; v[3] = cse[3];
      hred[wid][0][lane] = v;
#pragma unroll
      for (int rg = 0; rg < 4; ++rg) csd[rg] = cse[rg];
    }
    __syncthreads();
    if (wid < 4 && !(wid & 1)) {
      f32x4 v = hred[wid >> 1][0][lane];
      cw[0] = v[0]; cw[1] = v[1]; cw[2] = v[2]; cw[3] = v[3];
    }
    __syncthreads();
  }

  // ---- sent_feat = sent_out @ W_feat^T + b_feat ----
  {
    const int ug = gw & 31;
    const int unit = ug * 16 + lr;
    const ushort* wb = P.wfeat + (size_t)(ug * 16 + lr) * H + lk;
#pragma unroll
    for (int it = 0; it < 5; ++it) {
      int mt = (gw + it * 128) >> 5;
      f32x4 acc = (f32x4)0.0f;
      const ushort* ab = P.sent_out_bf + (size_t)(mt * 16 + lr) * H + lk;
#pragma unroll
      for (int k0 = 0; k0 < H; k0 += 32) {
        bf16x8 a = *reinterpret_cast<const bf16x8*>(ab + k0);
        bf16x8 b = *reinterpret_cast<const bf16x8*>(wb + k0);
        acc = __builtin_amdgcn_mfma_f32_16x16x32_bf16(a, b, acc, 0, 0, 0);
      }
#pragma unroll
      for (int rg = 0; rg < 4; ++rg) {
        int row = mt * 16 + orow + rg;
        P.sent_feat[(size_t)row * H + unit] = acc[rg] + P.b_feat[unit];
      }
    }
    sbar(P.sflags, bid, UBLK, ++ph);
  }

  // ---- hierarchical decoder ----
  {
    const int half = wid & 1;            // k-half (wid<4)
    const int ug2 = bid * 2 + (wid >> 1);
    const int unit2 = ug2 * 16 + lr;
    const int ug = bid * 2 + wid;        // full-k layout (wid<2)
    const int unit = ug * 16 + lr;

    for (int n = 0; n < NN; ++n) {
      bf16x8 wreg[4][8];
      if (wid < 4) {
#pragma unroll
        for (int g = 0; g < 4; ++g)
#pragma unroll
          for (int kk = 0; kk < 8; ++kk)
            wreg[g][kk] = *reinterpret_cast<const bf16x8*>(
                P.wdWh + (size_t)g * H * H + (size_t)(ug2 * 16 + lr) * H +
                half * 256 + kk * 32 + lk);
      }
      for (int t = 0; t < TT - 1; ++t) {
        int stp = n * (TT - 1) + t;
        f32x4 acc[4];
        if (wid < 4) {
          const ushort* A = (t == 0)
              ? ((n == 0) ? P.sh0 : P.final_bf)
              : P.wh_bf + (size_t)(stp - 1) * 16 * H;
#pragma unroll
          for (int g = 0; g < 4; ++g) acc[g] = (f32x4)0.0f;
          const ushort* ab = A + (size_t)lr * H + half * 256 + lk;
#pragma unroll
          for (int kk = 0; kk < 8; ++kk) {
            bf16x8 a = *reinterpret_cast<const bf16x8*>(ab + kk * 32);
#pragma unroll
            for (int g = 0; g < 4; ++g)
              acc[g] = __builtin_amdgcn_mfma_f32_16x16x32_bf16(a, wreg[g][kk], acc[g], 0, 0, 0);
          }
          if (half) {
#pragma unroll
            for (int g = 0; g < 4; ++g) hred[wid >> 1][g][lane] = acc[g];
          }
        }
        __syncthreads();
        if (wid < 4 && !half) {
#pragma unroll
          for (int g = 0; g < 4; ++g) acc[g] += hred[wid >> 1][g][lane];
#pragma unroll
          for (int rg = 0; rg < 4; ++rg) {
            int row = orow + rg;
            const ushort* xi = P.XiD + (size_t)(stp * 16 + row) * 2048 + unit2;
            float gi = acc[0][rg] + b2f(xi[0]);
            float gf = acc[1][rg] + b2f(xi[512]);
            float gc = acc[2][rg] + b2f(xi[1024]);
            float go = acc[3][rg] + b2f(xi[1536]);
            float c = sigmoidf_(gf) * cw[rg] + sigmoidf_(gi) * tanhf(gc);
            float h = sigmoidf_(go) * tanhf(c);
            cw[rg] = c;
            P.wh_bf[(size_t)(stp * 16 + row) * H + unit2] = f2b_rne(h);
          }
        }
        sbar(P.sflags, bid, UBLK, ++ph);
      }
      // sentence n's wh rows are globally visible -> release vocab tiles
      if (bid == 0 && tid == 0)
        __hip_atomic_store(P.vflag, 2u + (uint)n, __ATOMIC_RELEASE, SCOPE_AGENT);
      // ---- sentence-decoder LSTM step ----
      if (wid < 2) {
        f32x4 acc[4];
#pragma unroll
        for (int g = 0; g < 4; ++g) acc[g] = (f32x4)0.0f;
        const ushort* A1 = P.wh_bf + (size_t)(n * (TT - 1) + TT - 2) * 16 * H;
        const ushort* A2 = (n == 0) ? P.sh0 : P.final_bf;
        const ushort* ab1 = A1 + (size_t)lr * H + lk;
        const ushort* wb1 = P.sdWi + (size_t)(ug * 16 + lr) * H + lk;
#pragma unroll
        for (int k0 = 0; k0 < H; k0 += 32) {
          bf16x8 a = *reinterpret_cast<const bf16x8*>(ab1 + k0);
#pragma unroll
          for (int g = 0; g < 4; ++g) {
            bf16x8 b = *reinterpret_cast<const bf16x8*>(wb1 + (size_t)g * H * H + k0);
            acc[g] = __builtin_amdgcn_mfma_f32_16x16x32_bf16(a, b, acc[g], 0, 0, 0);
          }
        }
        const ushort* ab2 = A2 + (size_t)lr * H + lk;
        const ushort* wb2 = P.sdWh + (size_t)(ug * 16 + lr) * H + lk;
#pragma unroll
        for (int k0 = 0; k0 < H; k0 += 32) {
          bf16x8 a = *reinterpret_cast<const bf16x8*>(ab2 + k0);
#pragma unroll
          for (int g = 0; g < 4; ++g) {
            bf16x8 b = *reinterpret_cast<const bf16x8*>(wb2 + (size_t)g * H * H + k0);
            acc[g] = __builtin_amdgcn_mfma_f32_16x16x32_bf16(a, b, acc[g], 0, 0, 0);
          }
        }
#pragma unroll
        for (int rg = 0; rg < 4; ++rg) {
          int row = orow + rg;
          float gi = acc[0][rg] + P.sd_b[0 * H + unit];
          float gf = acc[1][rg] + P.sd_b[1 * H + unit];
          float gc = acc[2][rg] + P.sd_b[2 * H + unit];
          float go = acc[3][rg] + P.sd_b[3 * H + unit];
          float c = sigmoidf_(gf) * csd[rg] + sigmoidf_(gi) * tanhf(gc);
          float h = sigmoidf_(go) * tanhf(c);
          csd[rg] = c;
          P.sdh_bf[(size_t)row * H + unit] = f2b_rne(h);
        }
      }
      sbar(P.sflags, bid, UBLK, ++ph);
      // ---- qb = sdh @ attn_Wh^T ----
      if (wid < 2) {
        f32x4 acc = (f32x4)0.0f;
        const ushort* ab = P.sdh_bf + (size_t)lr * H + lk;
        const ushort* wb = P.attnWh + (size_t)(ug * 16 + lr) * H + lk;
#pragma unroll
        for (int k0 = 0; k0 < H; k0 += 32) {
          bf16x8 a = *reinterpret_cast<const bf16x8*>(ab + k0);
          bf16x8 b = *reinterpret_cast<const bf16x8*>(wb + k0);
          acc = __builtin_amdgcn_mfma_f32_16x16x32_bf16(a, b, acc, 0, 0, 0);
        }
#pragma unroll
        for (int rg = 0; rg < 4; ++rg)
          P.qb[(size_t)(orow + rg) * H + unit] = acc[rg];
      }
      sbar(P.sflags, bid, UBLK, ++ph);
      // ---- e[s,b] ----
      for (int sb = gw; sb < 320; sb += 128) {
        int b = sb & 15;
        float cov = P.covb[sb];
        float sum = 0.f;
        for (int h2 = lane; h2 < H; h2 += 64)
          sum += tanhf(P.sent_feat[(size_t)sb * H + h2] + P.qb[b * H + h2] +
                       cov * P.attn_wc[h2]) * P.attn_v[h2];
#pragma unroll
        for (int d = 1; d < 64; d <<= 1) sum += __shfl_xor(sum, d);
        if (lane == 0)
          P.ebuf[sb] = (P.articles[sb * LL] > 0) ? sum : -1e9f;
      }
      sbar(P.sflags, bid, UBLK, ++ph);
      // ---- softmax over s + coverage (block bid owns batch col b = bid) ----
      if (wid == 0) {
        int b = bid;
        float ev = (lane < SS) ? P.ebuf[lane * 16 + b] : -3.0e38f;
        float mx = ev;
#pragma unroll
        for (int d = 1; d < 64; d <<= 1) mx = fmaxf(mx, __shfl_xor(mx, d));
        float ex = (lane < SS) ? expf(ev - mx) : 0.f;
        float s = ex;
#pragma unroll
        for (int d = 1; d < 64; d <<= 1) s += __shfl_xor(s, d);
        float al = ex / s;
        float cl = 0.f;
        if (lane < SS) {
          int sb = lane * 16 + b;
          float cov = P.covb[sb];
          cl = fminf(al, cov);
          P.covb[sb] = cov + al;
          P.alignb[sb] = al;
        }
#pragma unroll
        for (int d = 1; d < 64; d <<= 1) cl += __shfl_xor(cl, d);
        if (lane == 0) atomicAdd(P.loss, cl * (1.f / BB));
      }
      __syncthreads();   // softmax col b=bid is block-local to context below
      // ---- context + catb = [ctx | sdh] for batch col b = bid ----
      {
        int b = bid, h2 = tid;
        float s = 0.f;
#pragma unroll
        for (int ss2 = 0; ss2 < SS; ++ss2)
          s += P.alignb[ss2 * 16 + b] * P.sent_out[(size_t)(ss2 * 16 + b) * H + h2];
        P.catb[b * 1024 + h2] = f2b_rne(s);
        P.catb[b * 1024 + 512 + h2] = P.sdh_bf[(size_t)b * H + h2];
      }
      sbar(P.sflags, bid, UBLK, ++ph);
      // ---- final = tanh(catb @ W_out^T + b_out) ----
      if (wid < 2) {
        f32x4 acc = (f32x4)0.0f;
        const ushort* ab = P.catb + (size_t)lr * 1024 + lk;
        const ushort* wb = P.Wout + (size_t)(ug * 16 + lr) * 1024 + lk;
#pragma unroll
        for (int k0 = 0; k0 < 1024; k0 += 32) {
          bf16x8 a = *reinterpret_cast<const bf16x8*>(ab + k0);
          bf16x8 b = *reinterpret_cast<const bf16x8*>(wb + k0);
          acc = __builtin_amdgcn_mfma_f32_16x16x32_bf16(a, b, acc, 0, 0, 0);
        }
#pragma unroll
        for (int rg = 0; rg < 4; ++rg) {
          int row = orow + rg;
          float v = tanhf(acc[rg] + P.b_out[unit]);
          P.final_bf[(size_t)row * H + unit] = f2b_rne(v);
        }
      }
      sbar(P.sflags, bid, UBLK, ++ph);
    }
    // final release so lagging vocab tiles can't miss sentence 5
    if (bid == 0 && tid == 0)
      __hip_atomic_store(P.vflag, 7u, __ATOMIC_RELEASE, SCOPE_AGENT);
  }
}

// target logit per decoder row (consistent bf16 operands)
__global__ void tlog_kernel(const ushort* __restrict__ wh_bf,
                            const ushort* __restrict__ Wv_bf,
                            const float* __restrict__ bv,
                            const int* __restrict__ summaries,
                            float* __restrict__ tlog)
{
  int row = blockIdx.x;
  int lane = threadIdx.x;
  int b = row & 15, stp = row >> 4;
  int n = stp / (TT - 1), t = stp % (TT - 1);
  int tgt = summaries[(n * BB + b) * TT + t + 1];
  float s = 0.f;
  for (int k = lane; k < H; k += 64)
    s += b2f(wh_bf[(size_t)row * H + k]) * b2f(Wv_bf[(size_t)tgt * H + k]);
#pragma unroll
  for (int d = 1; d < 64; d <<= 1) s += __shfl_xor(s, d);
  if (lane == 0) tlog[row] = s + bv[tgt];
}

// per-step masked-mean NLL from partials
__global__ __launch_bounds__(256) void nll_kernel(
    const float* __restrict__ partials, const float* __restrict__ tlog,
    const int* __restrict__ summaries, float* __restrict__ loss)
{
  int stp = blockIdx.x;
  int tid = threadIdx.x;
  int rr = tid >> 4, ch = tid & 15;
  int row = stp * 16 + rr;
  const float* pr = partials + (size_t)row * NT2 * 2;
  float mx = -3.0e38f;
  for (int t2 = ch; t2 < NT2; t2 += 16) mx = fmaxf(mx, pr[t2 * 2]);
#pragma unroll
  for (int d = 1; d < 16; d <<= 1) mx = fmaxf(mx, __shfl_xor(mx, d));
  float s = 0.f;
  for (int t2 = ch; t2 < NT2; t2 += 16) s += pr[t2 * 2 + 1] * expf(pr[t2 * 2] - mx);
#pragma unroll
  for (int d = 1; d < 16; d <<= 1) s += __shfl_xor(s, d);
  __shared__ float sh_n[16], sh_m[16];
  if (ch == 0) {
    float lse = mx + logf(s);
    float nll = lse - tlog[row];
    int b = row & 15;
    int n = stp / (TT - 1), t = stp % (TT - 1);
    int wa = summaries[(n * BB + b) * TT + t + 1];
    sh_n[rr] = (wa != 0) ? nll : 0.f;
    sh_m[rr] = (wa != 0) ? 1.f : 0.f;
  }
  __syncthreads();
  if (tid == 0) {
    float sn = 0.f, sm = 0.f;
    for (int r2 = 0; r2 < 16; ++r2) { sn += sh_n[r2]; sm += sh_m[r2]; }
    atomicAdd(loss, sn / fmaxf(sm, 1.f));
  }
}

// ---------------------------------------------------------------------------
extern "C" void kernel_launch(void* const* d_in, const int* in_sizes, int n_in,
                              void* d_out, int out_size, void* d_ws, size_t ws_size,
                              hipStream_t stream)
{
  (void)in_sizes; (void)n_in; (void)out_size; (void)ws_size;
  const int*   articles  = (const int*)d_in[0];
  const int*   summaries = (const int*)d_in[1];
  const float* emb_src   = (const float*)d_in[2];
  const float* emb_tgt   = (const float*)d_in[3];
  const float* we_Wi = (const float*)d_in[4];
  const float* we_Wh = (const float*)d_in[5];
  const float* we_b  = (const float*)d_in[6];
  const float* se_Wi = (const float*)d_in[7];
  const float* se_Wh = (const float*)d_in[8];
  const float* se_b  = (const float*)d_in[9];
  const float* W_feat = (const float*)d_in[10];
  const float* b_feat = (const float*)d_in[11];
  const float* wd_Wi = (const float*)d_in[12];
  const float* wd_Wh = (const float*)d_in[13];
  const float* wd_b  = (const float*)d_in[14];
  const float* W_vocab = (const float*)d_in[15];
  const float* b_vocab = (const float*)d_in[16];
  const float* sd_Wi = (const float*)d_in[17];
  const float* sd_Wh = (const float*)d_in[18];
  const float* sd_b  = (const float*)d_in[19];
  const float* attn_Wh = (const float*)d_in[20];
  const float* attn_wc = (const float*)d_in[21];
  const float* attn_v  = (const float*)d_in[22];
  const float* W_out = (const float*)d_in[23];
  const float* b_out = (const float*)d_in[24];

  char* wsb = (char*)d_ws;
  size_t off = 0;
  auto alloc = [&](size_t bytes) -> char* {
    char* p = wsb + off;
    off += (bytes + 255) & ~(size_t)255;
    return p;
  };

  // regA: A_we (prep->proj) UNION {wh_bf, partials, tlog} (mega onwards)
  char* regA = alloc(9830400);
  ushort* A_we     = (ushort*)regA;
  ushort* wh_bf    = (ushort*)regA;                    // 1856*512*2 = 1,900,544
  float*  partials = (float*)(regA + 1900544);         // 1856*120*2*4 = 1,781,760
  float*  tlogb    = (float*)(regA + 3682304);         // 1824*4

  ushort* A_wd = (ushort*)alloc((size_t)MROWS * H * 2);

  // regW: XiW bf16 (proj->mega word-enc) UNION Wv_bf (vocab role)
  char* regW = alloc((size_t)9600 * 2048 * 2);
  ushort* XiW   = (ushort*)regW;
  ushort* Wv_bf = (ushort*)regW;

  ushort* XiD = (ushort*)alloc((size_t)MROWS * 2048 * 2);

  ushort* weWi  = (ushort*)alloc(4 * H * H * 2);
  ushort* wdWi  = (ushort*)alloc(4 * H * H * 2);
  ushort* weWh  = (ushort*)alloc(4 * H * H * 2);
  ushort* seWi  = (ushort*)alloc(4 * H * H * 2);
  ushort* seWh  = (ushort*)alloc(4 * H * H * 2);
  ushort* wdWh  = (ushort*)alloc(4 * H * H * 2);
  ushort* sdWi  = (ushort*)alloc(4 * H * H * 2);
  ushort* sdWh  = (ushort*)alloc(4 * H * H * 2);
  ushort* wfeat = (ushort*)alloc(H * H * 2);
  ushort* attnWh= (ushort*)alloc(H * H * 2);
  ushort* Wout  = (ushort*)alloc(H * 2 * H * 2);

  float*  XiS = (float*)alloc((size_t)320 * 2048 * 4);
  ushort* h0  = (ushort*)alloc(320 * H * 2);
  ushort* h1  = (ushort*)alloc(320 * H * 2);
  ushort* sh0 = (ushort*)alloc(16 * H * 2);
  ushort* sh1 = (ushort*)alloc(16 * H * 2);
  float*  sent_out    = (float*)alloc(320 * H * 4);
  ushort* sent_out_bf = (ushort*)alloc(320 * H * 2);
  float*  sent_feat   = (float*)alloc(320 * H * 4);
  ushort* sdh_bf   = (ushort*)alloc(16 * H * 2);
  ushort* final_bf = (ushort*)alloc(16 * H * 2);
  ushort* catb     = (ushort*)alloc(16 * 1024 * 2);
  float*  qb       = (float*)alloc(16 * H * 4);
  float*  ebuf   = (float*)alloc(1280);
  float*  alignb = (float*)alloc(1280);
  float*  covb   = (float*)alloc(1280);
  uint*   sflags  = (uint*)alloc(UBLK * 16 * 4);
  uint*   vbflags = (uint*)alloc(NV * 16 * 4);
  uint*   vflag   = (uint*)alloc(256);

  float* loss = (float*)d_out;
  hipMemsetAsync(loss, 0, 4, stream);
  hipMemsetAsync(covb, 0, 1280, stream);
  hipMemsetAsync(h0, 0, 320 * H * 2, stream);
  hipMemsetAsync(sh0, 0, 16 * H * 2, stream);
  hipMemsetAsync(sflags, 0, UBLK * 16 * 4, stream);
  hipMemsetAsync(vbflags, 0, NV * 16 * 4, stream);
  hipMemsetAsync(vflag, 0, 256, stream);

  // 1) prep: gathers + weight conversions
  {
    PrepP P = {articles, summaries, emb_src, emb_tgt,
               we_Wi, wd_Wi, we_Wh, se_Wi, se_Wh, W_feat,
               wd_Wh, sd_Wi, sd_Wh, attn_Wh, W_out,
               A_we, A_wd, weWi, wdWi, weWh, seWi, seWh, wfeat,
               wdWh, sdWi, sdWh, attnWh, Wout};
    prep_kernel<<<2048, 256, 0, stream>>>(P);
  }

  // 2) input projections
  proj_mfma_kernel<<<1432, 512, 0, stream>>>(A_we, weWi, we_b, XiW,
                                             A_wd, wdWi, wd_b, XiD);

  // zero wh_bf pad rows (A_we dead after proj; stream-ordered)
  hipMemsetAsync((char*)wh_bf + (size_t)MROWS * H * 2, 0,
                 (size_t)(MPAD - MROWS) * H * 2, stream);

  // 3) MEGA: sequential chain (16 blocks) + concurrent vocab (232 blocks)
  {
    MP P;
    P.XiW = XiW; P.XiD = XiD;
    P.weWh = weWh; P.seWi = seWi; P.seWh = seWh; P.wfeat = wfeat;
    P.wdWh = wdWh; P.sdWi = sdWi; P.sdWh = sdWh; P.attnWh = attnWh; P.Wout = Wout;
    P.se_b = se_b; P.b_feat = b_feat; P.sd_b = sd_b; P.b_out = b_out;
    P.attn_wc = attn_wc; P.attn_v = attn_v; P.articles = articles;
    P.h0 = h0; P.h1 = h1; P.XiS = XiS; P.sh0 = sh0; P.sh1 = sh1;
    P.sent_out = sent_out; P.sent_out_bf = sent_out_bf; P.sent_feat = sent_feat;
    P.wh_bf = wh_bf; P.sdh_bf = sdh_bf; P.final_bf = final_bf; P.catb = catb;
    P.qb = qb; P.ebuf = ebuf; P.alignb = alignb; P.covb = covb; P.loss = loss;
    P.sflags = sflags; P.vbflags = vbflags; P.vflag = vflag;
    P.Wv = W_vocab; P.Wv_bf = Wv_bf; P.bv = b_vocab; P.partials = partials;
    mega_kernel<<<MEGA, 512, 0, stream>>>(P);
  }

  // 4) target logits + NLL
  tlog_kernel<<<MROWS, 64, 0, stream>>>(wh_bf, Wv_bf, b_vocab, summaries, tlogb);
  nll_kernel<<<NSTEPS, 256, 0, stream>>>(partials, tlogb, summaries, loss);
}